// Round 1
// baseline (2797.078 us; speedup 1.0000x reference)
//
#include <hip/hip_runtime.h>

#define D 128

// ---------------------------------------------------------------------------
// Kernel 1: fused dual GEMM
//   support1 = x @ W            (written to workspace)
//   out      = x @ W_skip + b   (initializes d_out; agg is atomically added later)
// W and W_skip (64 KiB each) are staged in LDS once per block.
// Each wave processes 4 rows per iteration; lane l owns output columns 2l, 2l+1.
// x-row elements are broadcast from registers via __shfl (readlane), so the
// inner loop is 16 FMA : 2 ds_read_b64 per k.
// ---------------------------------------------------------------------------
__global__ __launch_bounds__(512) void dual_gemm_kernel(
    const float* __restrict__ x, const float* __restrict__ W,
    const float* __restrict__ Ws, const float* __restrict__ b,
    float* __restrict__ s1, float* __restrict__ out, int N)
{
    __shared__ float sW[D * D];    // 64 KiB
    __shared__ float sWs[D * D];   // 64 KiB  (128 KiB total, 1 block/CU)

    const int t = threadIdx.x;
    for (int i = t * 4; i < D * D; i += 512 * 4) {
        *(float4*)&sW[i]  = *(const float4*)&W[i];
        *(float4*)&sWs[i] = *(const float4*)&Ws[i];
    }
    __syncthreads();

    const int lane   = t & 63;
    const int wave   = blockIdx.x * 8 + (t >> 6);
    const int nwaves = gridDim.x * 8;
    const int j      = lane * 2;            // two consecutive output columns
    const float2 bb  = *(const float2*)&b[j];

    for (int r0 = wave * 4; r0 < N; r0 += nwaves * 4) {
        // N = 100000 is a multiple of 4 and strides are multiples of 4,
        // so r0+3 < N whenever r0 < N.
        float2 xr[4];
#pragma unroll
        for (int r = 0; r < 4; ++r)
            xr[r] = *(const float2*)&x[(size_t)(r0 + r) * D + j];

        float2 a1[4], a2[4];
#pragma unroll
        for (int r = 0; r < 4; ++r) {
            a1[r] = make_float2(0.f, 0.f);
            a2[r] = make_float2(0.f, 0.f);
        }

#pragma unroll 8
        for (int k = 0; k < D; ++k) {
            const float2 wk  = *(const float2*)&sW[k * D + j];
            const float2 wsk = *(const float2*)&sWs[k * D + j];
#pragma unroll
            for (int r = 0; r < 4; ++r) {
                const float xv = __shfl((k & 1) ? xr[r].y : xr[r].x, k >> 1, 64);
                a1[r].x = fmaf(xv, wk.x,  a1[r].x);
                a1[r].y = fmaf(xv, wk.y,  a1[r].y);
                a2[r].x = fmaf(xv, wsk.x, a2[r].x);
                a2[r].y = fmaf(xv, wsk.y, a2[r].y);
            }
        }

#pragma unroll
        for (int r = 0; r < 4; ++r) {
            *(float2*)&s1[(size_t)(r0 + r) * D + j]  = a1[r];
            *(float2*)&out[(size_t)(r0 + r) * D + j] =
                make_float2(a2[r].x + bb.x, a2[r].y + bb.y);
        }
    }
}

// ---------------------------------------------------------------------------
// Kernel 2: edge-parallel SpMM scatter
//   out[rows[e], :] += edge_w[e] * support1[cols[e], :]
// One wave per edge; lane l handles columns 2l, 2l+1 (coalesced float2 gather,
// 2 HW fp32 atomics). Each wave owns a contiguous chunk of edges so the
// per-edge index loads are wave-uniform and stream through the cache.
// ---------------------------------------------------------------------------
__global__ __launch_bounds__(256) void spmm_edges_kernel(
    const float* __restrict__ s1, const int* __restrict__ rows,
    const int* __restrict__ cols, const float* __restrict__ ew,
    float* __restrict__ out, int E)
{
    const int lane   = threadIdx.x & 63;
    const int wave   = blockIdx.x * (blockDim.x >> 6) + (threadIdx.x >> 6);
    const int nw     = gridDim.x * (blockDim.x >> 6);
    const int j      = lane * 2;

    const int epw    = (E + nw - 1) / nw;          // edges per wave
    const int e_beg  = wave * epw;
    const int e_end  = min(e_beg + epw, E);

    for (int e = e_beg; e < e_end; ++e) {
        const int   r = rows[e];
        const int   c = cols[e];
        const float w = ew[e];

        const float2 v = *(const float2*)&s1[(size_t)c * D + j];
        float* o = &out[(size_t)r * D + j];
        unsafeAtomicAdd(o,     w * v.x);
        unsafeAtomicAdd(o + 1, w * v.y);
    }
}

// ---------------------------------------------------------------------------
extern "C" void kernel_launch(void* const* d_in, const int* in_sizes, int n_in,
                              void* d_out, int out_size, void* d_ws, size_t ws_size,
                              hipStream_t stream) {
    const float* x    = (const float*)d_in[0];
    const int*   rows = (const int*)  d_in[1];
    const int*   cols = (const int*)  d_in[2];
    const float* ew   = (const float*)d_in[3];
    const float* W    = (const float*)d_in[4];
    const float* Ws   = (const float*)d_in[5];
    const float* b    = (const float*)d_in[6];
    float*       out  = (float*)d_out;

    const int N = in_sizes[0] / D;
    const int E = in_sizes[1];

    float* s1 = (float*)d_ws;   // N*D floats = 51.2 MB workspace for support1

    // Dual GEMM: 768 blocks x 512 thr (8 waves), grid-strided over rows.
    dual_gemm_kernel<<<768, 512, 0, stream>>>(x, W, Ws, b, s1, out, N);

    // SpMM: 2048 blocks x 256 thr = 8192 waves (full device occupancy).
    spmm_edges_kernel<<<2048, 256, 0, stream>>>(s1, rows, cols, ew, out, E);
}

// Round 2
// 1045.338 us; speedup vs baseline: 2.6758x; 2.6758x over previous
//
#include <hip/hip_runtime.h>

#define D 128

// ---------------------------------------------------------------------------
// Kernel 1: fused dual GEMM
//   support1 = x @ W            (written to workspace)
//   out      = x @ W_skip + b   (initializes d_out; agg added by spmm_csr)
// ---------------------------------------------------------------------------
__global__ __launch_bounds__(512) void dual_gemm_kernel(
    const float* __restrict__ x, const float* __restrict__ W,
    const float* __restrict__ Ws, const float* __restrict__ b,
    float* __restrict__ s1, float* __restrict__ out, int N)
{
    __shared__ float sW[D * D];    // 64 KiB
    __shared__ float sWs[D * D];   // 64 KiB

    const int t = threadIdx.x;
    for (int i = t * 4; i < D * D; i += 512 * 4) {
        *(float4*)&sW[i]  = *(const float4*)&W[i];
        *(float4*)&sWs[i] = *(const float4*)&Ws[i];
    }
    __syncthreads();

    const int lane   = t & 63;
    const int wave   = blockIdx.x * 8 + (t >> 6);
    const int nwaves = gridDim.x * 8;
    const int j      = lane * 2;
    const float2 bb  = *(const float2*)&b[j];

    for (int r0 = wave * 4; r0 < N; r0 += nwaves * 4) {
        float2 xr[4];
#pragma unroll
        for (int r = 0; r < 4; ++r)
            xr[r] = *(const float2*)&x[(size_t)(r0 + r) * D + j];

        float2 a1[4], a2[4];
#pragma unroll
        for (int r = 0; r < 4; ++r) {
            a1[r] = make_float2(0.f, 0.f);
            a2[r] = make_float2(0.f, 0.f);
        }

#pragma unroll 8
        for (int k = 0; k < D; ++k) {
            const float2 wk  = *(const float2*)&sW[k * D + j];
            const float2 wsk = *(const float2*)&sWs[k * D + j];
#pragma unroll
            for (int r = 0; r < 4; ++r) {
                const float xv = __shfl((k & 1) ? xr[r].y : xr[r].x, k >> 1, 64);
                a1[r].x = fmaf(xv, wk.x,  a1[r].x);
                a1[r].y = fmaf(xv, wk.y,  a1[r].y);
                a2[r].x = fmaf(xv, wsk.x, a2[r].x);
                a2[r].y = fmaf(xv, wsk.y, a2[r].y);
            }
        }

#pragma unroll
        for (int r = 0; r < 4; ++r) {
            *(float2*)&s1[(size_t)(r0 + r) * D + j]  = a1[r];
            *(float2*)&out[(size_t)(r0 + r) * D + j] =
                make_float2(a2[r].x + bb.x, a2[r].y + bb.y);
        }
    }
}

// ---------------------------------------------------------------------------
// CSR build, pass A: histogram of destination rows
// ---------------------------------------------------------------------------
__global__ __launch_bounds__(256) void hist_kernel(
    const int* __restrict__ rows, int* __restrict__ hist, int E)
{
    int i = blockIdx.x * blockDim.x + threadIdx.x;
    const int stride = gridDim.x * blockDim.x;
    for (; i < E; i += stride)
        atomicAdd(&hist[rows[i]], 1);
}

// ---------------------------------------------------------------------------
// CSR build, pass B: exclusive prefix sum over N counts (single block).
// Writes rowptr[0..N] and a working copy cur[0..N-1].
// ---------------------------------------------------------------------------
__global__ __launch_bounds__(1024) void scan_kernel(
    const int* __restrict__ hist, int* __restrict__ rowptr,
    int* __restrict__ cur, int N)
{
    __shared__ int part[1024];
    const int t = threadIdx.x;
    const int chunk = (N + 1023) / 1024;
    const int beg = t * chunk;
    const int end = min(beg + chunk, N);

    int s = 0;
    for (int i = beg; i < end; ++i) s += hist[i];
    part[t] = s;
    __syncthreads();

    // Hillis-Steele inclusive scan over the 1024 partials
    for (int off = 1; off < 1024; off <<= 1) {
        int v = (t >= off) ? part[t - off] : 0;
        __syncthreads();
        part[t] += v;
        __syncthreads();
    }

    int excl = (t == 0) ? 0 : part[t - 1];
    for (int i = beg; i < end; ++i) {
        rowptr[i] = excl;
        cur[i]    = excl;
        excl += hist[i];
    }
    if (t == 1023) rowptr[N] = excl;   // == E
}

// ---------------------------------------------------------------------------
// CSR build, pass C: permute (col, w) pairs into row-sorted order.
// ---------------------------------------------------------------------------
__global__ __launch_bounds__(256) void scatter_kernel(
    const int* __restrict__ rows, const int* __restrict__ cols,
    const float* __restrict__ ew, int* __restrict__ cur,
    int2* __restrict__ se, int E)
{
    int i = blockIdx.x * blockDim.x + threadIdx.x;
    const int stride = gridDim.x * blockDim.x;
    for (; i < E; i += stride) {
        const int r = rows[i];
        const int slot = atomicAdd(&cur[r], 1);
        se[slot] = make_int2(cols[i], __float_as_int(ew[i]));
    }
}

// ---------------------------------------------------------------------------
// Pass D: row-parallel SpMM. One wave per row; lane l owns cols 2l, 2l+1.
// No atomics: register accumulate, single non-atomic out[r] += acc.
// Edge list reads are contiguous (row-sorted); s1 gathers coalesced float2.
// ---------------------------------------------------------------------------
__global__ __launch_bounds__(256) void spmm_csr_kernel(
    const float* __restrict__ s1, const int* __restrict__ rowptr,
    const int2* __restrict__ se, float* __restrict__ out, int N)
{
    const int lane = threadIdx.x & 63;
    const int wave = blockIdx.x * 4 + (threadIdx.x >> 6);
    const int nw   = gridDim.x * 4;
    const int j    = lane * 2;

    for (int r = wave; r < N; r += nw) {
        const int beg = rowptr[r];
        const int end = rowptr[r + 1];

        float2 acc = make_float2(0.f, 0.f);
        int e = beg;
        for (; e + 4 <= end; e += 4) {
            const int2 e0 = se[e + 0];
            const int2 e1 = se[e + 1];
            const int2 e2 = se[e + 2];
            const int2 e3 = se[e + 3];
            const float2 v0 = *(const float2*)&s1[(size_t)e0.x * D + j];
            const float2 v1 = *(const float2*)&s1[(size_t)e1.x * D + j];
            const float2 v2 = *(const float2*)&s1[(size_t)e2.x * D + j];
            const float2 v3 = *(const float2*)&s1[(size_t)e3.x * D + j];
            const float w0 = __int_as_float(e0.y), w1 = __int_as_float(e1.y);
            const float w2 = __int_as_float(e2.y), w3 = __int_as_float(e3.y);
            acc.x = fmaf(w0, v0.x, acc.x);  acc.y = fmaf(w0, v0.y, acc.y);
            acc.x = fmaf(w1, v1.x, acc.x);  acc.y = fmaf(w1, v1.y, acc.y);
            acc.x = fmaf(w2, v2.x, acc.x);  acc.y = fmaf(w2, v2.y, acc.y);
            acc.x = fmaf(w3, v3.x, acc.x);  acc.y = fmaf(w3, v3.y, acc.y);
        }
        for (; e < end; ++e) {
            const int2 ev = se[e];
            const float2 v = *(const float2*)&s1[(size_t)ev.x * D + j];
            const float w = __int_as_float(ev.y);
            acc.x = fmaf(w, v.x, acc.x);
            acc.y = fmaf(w, v.y, acc.y);
        }

        float2 o = *(float2*)&out[(size_t)r * D + j];
        o.x += acc.x;
        o.y += acc.y;
        *(float2*)&out[(size_t)r * D + j] = o;
    }
}

// ---------------------------------------------------------------------------
// Fallback (ws too small): round-1 edge-parallel atomic scatter.
// ---------------------------------------------------------------------------
__global__ __launch_bounds__(256) void spmm_edges_kernel(
    const float* __restrict__ s1, const int* __restrict__ rows,
    const int* __restrict__ cols, const float* __restrict__ ew,
    float* __restrict__ out, int E)
{
    const int lane = threadIdx.x & 63;
    const int wave = blockIdx.x * (blockDim.x >> 6) + (threadIdx.x >> 6);
    const int nw   = gridDim.x * (blockDim.x >> 6);
    const int j    = lane * 2;

    const int epw   = (E + nw - 1) / nw;
    const int e_beg = wave * epw;
    const int e_end = min(e_beg + epw, E);

    for (int e = e_beg; e < e_end; ++e) {
        const int   r = rows[e];
        const int   c = cols[e];
        const float w = ew[e];
        const float2 v = *(const float2*)&s1[(size_t)c * D + j];
        float* o = &out[(size_t)r * D + j];
        unsafeAtomicAdd(o,     w * v.x);
        unsafeAtomicAdd(o + 1, w * v.y);
    }
}

// ---------------------------------------------------------------------------
extern "C" void kernel_launch(void* const* d_in, const int* in_sizes, int n_in,
                              void* d_out, int out_size, void* d_ws, size_t ws_size,
                              hipStream_t stream) {
    const float* x    = (const float*)d_in[0];
    const int*   rows = (const int*)  d_in[1];
    const int*   cols = (const int*)  d_in[2];
    const float* ew   = (const float*)d_in[3];
    const float* W    = (const float*)d_in[4];
    const float* Ws   = (const float*)d_in[5];
    const float* b    = (const float*)d_in[6];
    float*       out  = (float*)d_out;

    const int N = in_sizes[0] / D;
    const int E = in_sizes[1];

    // Workspace layout:
    //   s1      : N*D floats (51.2 MB)
    //   hist    : N ints
    //   rowptr  : N+1 ints
    //   cur     : N ints      (+1 pad int for 8B alignment of se)
    //   se      : E int2 (col, weight-bits), row-sorted (25.6 MB)
    const size_t s1_bytes = (size_t)N * D * sizeof(float);
    const size_t int_cnt  = (size_t)3 * N + 2;               // hist+rowptr+cur+pad
    const size_t need     = s1_bytes + int_cnt * 4 + (size_t)E * 8;

    float* s1 = (float*)d_ws;

    // Dual GEMM initializes s1 and out(+skip+bias).
    dual_gemm_kernel<<<768, 512, 0, stream>>>(x, W, Ws, b, s1, out, N);

    if (ws_size >= need) {
        int*  ibase  = (int*)((char*)d_ws + s1_bytes);
        int*  hist   = ibase;                 // N
        int*  rowptr = ibase + N;             // N+1
        int*  cur    = ibase + 2 * N + 1;     // N
        int2* se     = (int2*)(ibase + 3 * N + 2);

        hipMemsetAsync(hist, 0, (size_t)N * 4, stream);
        hist_kernel   <<<2048, 256, 0, stream>>>(rows, hist, E);
        scan_kernel   <<<1,   1024, 0, stream>>>(hist, rowptr, cur, N);
        scatter_kernel<<<2048, 256, 0, stream>>>(rows, cols, ew, cur, se, E);
        spmm_csr_kernel<<<2048, 256, 0, stream>>>(s1, rowptr, se, out, N);
    } else {
        // Fallback: atomic edge-parallel scatter.
        spmm_edges_kernel<<<2048, 256, 0, stream>>>(s1, rows, cols, ew, out, E);
    }
}